// Round 8
// baseline (334.324 us; speedup 1.0000x reference)
//
#include <hip/hip_runtime.h>
#include <math.h>

// corr: (B=8, HW=4096, H=64, W=64) fp32. out same shape.
// out[b,s,p] = corr[b,s,p] * g[sy-iy(p)] * g[sx-ix(p)], idx(p)=argmax_s corr[b,s,p].
//
// All-linear access plan: per 2-batch group (128MB slab, L3-resident),
//   A: row-streaming argmax -> packed u64 atomicMax into fid
//   B: row-streaming multiply (reads hit L3), nontemporal stores.
constexpr int Bc   = 8;
constexpr int HWc  = 4096;
constexpr int GRP  = 2;                    // batches per group
constexpr int NR   = 32;                   // rows per block (32*64=2048 s-range, sy const)
constexpr int NTHR = 512;

typedef float f32x4 __attribute__((ext_vector_type(4)));

__device__ __forceinline__ unsigned monokey(float f) {
    unsigned u = __float_as_uint(f);
    return u ^ ((unsigned)(((int)u) >> 31) | 0x80000000u);
}

// ---------------------------------------------------------------------------
// A: argmax partials for GRP batches. Block = (batch, px-half, 32-row range).
// grid = GRP * 2 * (4096/NR) = 512 blocks x 512 thr. Thread owns 4 pixels,
// reads float4 per row -> block reads 32 x 8KB contiguous segments (linear).
// Packed key (monokey(max)<<32 | 4095-idx): atomicMax is order-independent,
// larger (4095-idx) wins ties == first occurrence == jnp.argmax. Safe vs
// 0xAA ws poison (real keys always larger) and idempotent across replays.
// ---------------------------------------------------------------------------
__global__ __launch_bounds__(NTHR, 8) void k_argmax(
        const float* __restrict__ corr, int b0,
        unsigned long long* __restrict__ fid) {
    int bl  = blockIdx.x & 1;                     // batch within group
    int ph  = (blockIdx.x >> 1) & 1;              // pixel half (2048 px)
    int rbk = blockIdx.x >> 2;                    // 0..127: 32-row range
    int b   = b0 + bl;
    int s0  = rbk * NR;
    int px0 = ph * 2048 + threadIdx.x * 4;

    const float* src = corr + (size_t)b * HWc * HWc + (size_t)s0 * HWc + px0;

    float bm0 = -INFINITY, bm1 = -INFINITY, bm2 = -INFINITY, bm3 = -INFINITY;
    int   bi0 = 0, bi1 = 0, bi2 = 0, bi3 = 0;

    #pragma unroll
    for (int c = 0; c < NR / 4; ++c) {            // 4 loads in flight
        float4 v[4];
        #pragma unroll
        for (int t = 0; t < 4; ++t)
            v[t] = *reinterpret_cast<const float4*>(src + (size_t)(c * 4 + t) * HWc);
        #pragma unroll
        for (int t = 0; t < 4; ++t) {
            int k = s0 + c * 4 + t;
            if (v[t].x > bm0) { bm0 = v[t].x; bi0 = k; }
            if (v[t].y > bm1) { bm1 = v[t].y; bi1 = k; }
            if (v[t].z > bm2) { bm2 = v[t].z; bi2 = k; }
            if (v[t].w > bm3) { bm3 = v[t].w; bi3 = k; }
        }
    }

    unsigned long long* f = fid + ((size_t)b << 12) + px0;
    atomicMax(&f[0], ((unsigned long long)monokey(bm0) << 32) | (unsigned)(4095 - bi0));
    atomicMax(&f[1], ((unsigned long long)monokey(bm1) << 32) | (unsigned)(4095 - bi1));
    atomicMax(&f[2], ((unsigned long long)monokey(bm2) << 32) | (unsigned)(4095 - bi2));
    atomicMax(&f[3], ((unsigned long long)monokey(bm3) << 32) | (unsigned)(4095 - bi3));
}

// ---------------------------------------------------------------------------
// B: apply pass, same geometry as A (all-linear). sy = s0>>6 is constant per
// block; gy per pixel hoisted to regs. gx = gtab[r + (63-ix)] one LDS read
// per element. corr reads hit L3 (slab just staged by A); nontemporal stores
// keep the output stream from evicting the slab.
// ---------------------------------------------------------------------------
__global__ __launch_bounds__(NTHR, 8) void k_apply(
        const float* __restrict__ corr, int b0,
        const unsigned long long* __restrict__ fid, float* __restrict__ out) {
    int bl  = blockIdx.x & 1;
    int ph  = (blockIdx.x >> 1) & 1;
    int rbk = blockIdx.x >> 2;
    int b   = b0 + bl;
    int s0  = rbk * NR;
    int sy  = s0 >> 6;
    int px0 = ph * 2048 + threadIdx.x * 4;

    __shared__ float gtab[128];                   // g[d+63], d in [-63,63]
    if (threadIdx.x < 128) {
        float d = (float)((int)threadIdx.x - 63);
        gtab[threadIdx.x] = __expf(-d * d * (1.0f / 50.0f));   // 2*sigma^2 = 50
    }
    __syncthreads();

    const unsigned long long* f = fid + ((size_t)b << 12) + px0;
    ulonglong2 q0 = *reinterpret_cast<const ulonglong2*>(f);
    ulonglong2 q1 = *reinterpret_cast<const ulonglong2*>(f + 2);
    int i0 = 4095 - (int)(unsigned)(q0.x & 0xFFFFFFFFull);
    int i1 = 4095 - (int)(unsigned)(q0.y & 0xFFFFFFFFull);
    int i2 = 4095 - (int)(unsigned)(q1.x & 0xFFFFFFFFull);
    int i3 = 4095 - (int)(unsigned)(q1.y & 0xFFFFFFFFull);

    float gy0 = gtab[sy - (i0 >> 6) + 63];
    float gy1 = gtab[sy - (i1 >> 6) + 63];
    float gy2 = gtab[sy - (i2 >> 6) + 63];
    float gy3 = gtab[sy - (i3 >> 6) + 63];
    int ic0 = 63 - (i0 & 63) + ((s0 & 63));       // gx(r) = gtab[ic + r]
    int ic1 = 63 - (i1 & 63) + ((s0 & 63));
    int ic2 = 63 - (i2 & 63) + ((s0 & 63));
    int ic3 = 63 - (i3 & 63) + ((s0 & 63));

    size_t base = (size_t)b * HWc * HWc + (size_t)s0 * HWc + px0;
    const float* cs = corr + base;
    float*       os = out  + base;

    #pragma unroll 4
    for (int r = 0; r < NR; ++r) {                // s = s0 + r; sx = (s0&63)+r
        float4 v = *reinterpret_cast<const float4*>(cs + (size_t)r * HWc);
        f32x4 o;
        o.x = v.x * gy0 * gtab[ic0 + r];
        o.y = v.y * gy1 * gtab[ic1 + r];
        o.z = v.z * gy2 * gtab[ic2 + r];
        o.w = v.w * gy3 * gtab[ic3 + r];
        __builtin_nontemporal_store(o, reinterpret_cast<f32x4*>(os + (size_t)r * HWc));
    }
}

extern "C" void kernel_launch(void* const* d_in, const int* in_sizes, int n_in,
                              void* d_out, int out_size, void* d_ws, size_t ws_size,
                              hipStream_t stream) {
    const float* corr = (const float*)d_in[0];
    float* out = (float*)d_out;
    unsigned long long* fid = (unsigned long long*)d_ws;   // 8*4096 u64 = 256 KB

    constexpr int NB = GRP * 2 * (HWc / NR);      // 512 blocks per launch
    for (int g = 0; g < Bc / GRP; ++g) {
        int b0 = g * GRP;
        k_argmax<<<NB, NTHR, 0, stream>>>(corr, b0, fid);
        k_apply <<<NB, NTHR, 0, stream>>>(corr, b0, fid, out);
    }
}